// Round 1
// baseline (1813.917 us; speedup 1.0000x reference)
//
#include <hip/hip_runtime.h>
#include <cstdint>
#include <cstddef>

using f4 = __attribute__((ext_vector_type(4))) float;

constexpr int Bn  = 2;
constexpr int Sn  = 2048;
constexpr int Dn  = 1024;   // D_IN == D_MODEL
constexpr int Hn  = 16;
constexpr int DHn = 64;

// XOR swizzle for [64][64] float LDS tiles: spreads row-strided b128 reads
// across banks (bank depends on row bits 2..4). Keeps 16B alignment.
__device__ __forceinline__ int swz(int row, int col) {
    return (row << 6) + (col ^ (((row >> 2) & 7) << 2));
}

// ---------------- QKV projection GEMM, head-split output ----------------
// A[M=4096, K=1024] @ W[K,N=1024] + bias -> O in [B,H,S,DEPTH] layout.
__global__ __launch_bounds__(256)
void qkv_proj_kernel(const float* __restrict__ q_in, const float* __restrict__ k_in,
                     const float* __restrict__ v_in,
                     const float* __restrict__ Wq, const float* __restrict__ bq,
                     const float* __restrict__ Wk, const float* __restrict__ bk,
                     const float* __restrict__ Wv, const float* __restrict__ bv,
                     float* __restrict__ qh, float* __restrict__ kh, float* __restrict__ vh)
{
    const int which = blockIdx.z;
    const float* __restrict__ A    = which == 0 ? q_in : (which == 1 ? k_in : v_in);
    const float* __restrict__ W    = which == 0 ? Wq   : (which == 1 ? Wk   : Wv);
    const float* __restrict__ bias = which == 0 ? bq   : (which == 1 ? bk   : bv);
    float* __restrict__ O          = which == 0 ? qh   : (which == 1 ? kh   : vh);

    const int tid = threadIdx.x;
    const int tx = tid & 15, ty = tid >> 4;
    const int n0 = blockIdx.x << 6;
    const int m0 = blockIdx.y << 6;

    __shared__ float As[16][68];   // [k][m], padded
    __shared__ float Bs[16][68];   // [k][n], padded

    float acc[4][4] = {};

    const int alr = tid >> 2,  alk = (tid & 3) << 2;    // A load: row 0..63, k 0..12
    const int blr = tid >> 4,  blc = (tid & 15) << 2;   // W load: k 0..15, n 0..60

    for (int k0 = 0; k0 < Dn; k0 += 16) {
        f4 av = *(const f4*)&A[(size_t)(m0 + alr) * Dn + k0 + alk];
        f4 wv = *(const f4*)&W[(size_t)(k0 + blr) * Dn + n0 + blc];
        As[alk + 0][alr] = av[0];
        As[alk + 1][alr] = av[1];
        As[alk + 2][alr] = av[2];
        As[alk + 3][alr] = av[3];
        *(f4*)&Bs[blr][blc] = wv;
        __syncthreads();
        #pragma unroll
        for (int kk = 0; kk < 16; ++kk) {
            f4 a = *(const f4*)&As[kk][ty << 2];
            f4 b = *(const f4*)&Bs[kk][tx << 2];
            #pragma unroll
            for (int i = 0; i < 4; ++i)
                #pragma unroll
                for (int j = 0; j < 4; ++j)
                    acc[i][j] = fmaf(a[i], b[j], acc[i][j]);
        }
        __syncthreads();
    }

    const int h = n0 >> 6;            // BN=64 == DEPTH, tile maps to one head
    f4 bia = *(const f4*)&bias[n0 + (tx << 2)];
    #pragma unroll
    for (int i = 0; i < 4; ++i) {
        const int m = m0 + (ty << 2) + i;
        const int b = m >> 11, s = m & (Sn - 1);
        f4 o;
        o[0] = acc[i][0] + bia[0];
        o[1] = acc[i][1] + bia[1];
        o[2] = acc[i][2] + bia[2];
        o[3] = acc[i][3] + bia[3];
        *(f4*)&O[((((size_t)b * Hn + h) * Sn + s) << 6) + (tx << 2)] = o;
    }
}

// ---------------- output projection GEMM (plain layout) ----------------
__global__ __launch_bounds__(256)
void oproj_kernel(const float* __restrict__ A, const float* __restrict__ W,
                  const float* __restrict__ bias, float* __restrict__ out)
{
    const int tid = threadIdx.x;
    const int tx = tid & 15, ty = tid >> 4;
    const int n0 = blockIdx.x << 6;
    const int m0 = blockIdx.y << 6;

    __shared__ float As[16][68];
    __shared__ float Bs[16][68];

    float acc[4][4] = {};

    const int alr = tid >> 2,  alk = (tid & 3) << 2;
    const int blr = tid >> 4,  blc = (tid & 15) << 2;

    for (int k0 = 0; k0 < Dn; k0 += 16) {
        f4 av = *(const f4*)&A[(size_t)(m0 + alr) * Dn + k0 + alk];
        f4 wv = *(const f4*)&W[(size_t)(k0 + blr) * Dn + n0 + blc];
        As[alk + 0][alr] = av[0];
        As[alk + 1][alr] = av[1];
        As[alk + 2][alr] = av[2];
        As[alk + 3][alr] = av[3];
        *(f4*)&Bs[blr][blc] = wv;
        __syncthreads();
        #pragma unroll
        for (int kk = 0; kk < 16; ++kk) {
            f4 a = *(const f4*)&As[kk][ty << 2];
            f4 b = *(const f4*)&Bs[kk][tx << 2];
            #pragma unroll
            for (int i = 0; i < 4; ++i)
                #pragma unroll
                for (int j = 0; j < 4; ++j)
                    acc[i][j] = fmaf(a[i], b[j], acc[i][j]);
        }
        __syncthreads();
    }

    f4 bia = *(const f4*)&bias[n0 + (tx << 2)];
    #pragma unroll
    for (int i = 0; i < 4; ++i) {
        const int m = m0 + (ty << 2) + i;
        f4 o;
        o[0] = acc[i][0] + bia[0];
        o[1] = acc[i][1] + bia[1];
        o[2] = acc[i][2] + bia[2];
        o[3] = acc[i][3] + bia[3];
        *(f4*)&out[(size_t)m * Dn + n0 + (tx << 2)] = o;
    }
}

// ---------------- fused attention per (b,h, 64-row q tile) ----------------
// Phase 1: stream K tiles, online (m,l). Phase 2: recompute logits, write
// normalized attn to d_out, accumulate ctx = P @ V via LDS P tile.
__global__ __launch_bounds__(256)
void attn_kernel(const float* __restrict__ qh, const float* __restrict__ kh,
                 const float* __restrict__ vh, const float* __restrict__ mask,
                 float* __restrict__ attn, float* __restrict__ ctx)
{
    const int bh = blockIdx.y;
    const int b  = bh >> 4, h = bh & 15;
    const int q0 = blockIdx.x << 6;
    const int tid = threadIdx.x;
    const int tx = tid & 15, ty = tid >> 4;

    __shared__ float Qs[4096];
    __shared__ float Ks[4096];
    __shared__ float Vs[4096];
    __shared__ float Ps[4096];

    const float* __restrict__ Qg = qh + ((size_t)bh * Sn + q0) * DHn;
    const float* __restrict__ Kg = kh + (size_t)bh * Sn * DHn;
    const float* __restrict__ Vg = vh + (size_t)bh * Sn * DHn;
    const float* __restrict__ mg = mask + (size_t)b * Sn;

    const int lr = tid >> 4;            // 0..15
    const int lc = (tid & 15) << 2;     // 0..60

    #pragma unroll
    for (int p = 0; p < 4; ++p) {
        const int r = lr + (p << 4);
        *(f4*)&Qs[swz(r, lc)] = *(const f4*)&Qg[(size_t)r * DHn + lc];
    }

    float m_run[4], l_run[4];
    #pragma unroll
    for (int i = 0; i < 4; ++i) { m_run[i] = -3.0e38f; l_run[i] = 0.0f; }

    // -------- phase 1: row stats --------
    for (int kt = 0; kt < Sn / 64; ++kt) {
        const int k0 = kt << 6;
        __syncthreads();
        #pragma unroll
        for (int p = 0; p < 4; ++p) {
            const int r = lr + (p << 4);
            *(f4*)&Ks[swz(r, lc)] = *(const f4*)&Kg[(size_t)(k0 + r) * DHn + lc];
        }
        __syncthreads();

        float sacc[4][4] = {};
        #pragma unroll
        for (int d = 0; d < 64; d += 4) {
            f4 qv[4], kv[4];
            #pragma unroll
            for (int i = 0; i < 4; ++i) qv[i] = *(const f4*)&Qs[swz((ty << 2) + i, d)];
            #pragma unroll
            for (int j = 0; j < 4; ++j) kv[j] = *(const f4*)&Ks[swz((tx << 2) + j, d)];
            #pragma unroll
            for (int i = 0; i < 4; ++i)
                #pragma unroll
                for (int j = 0; j < 4; ++j) {
                    sacc[i][j] = fmaf(qv[i][0], kv[j][0], sacc[i][j]);
                    sacc[i][j] = fmaf(qv[i][1], kv[j][1], sacc[i][j]);
                    sacc[i][j] = fmaf(qv[i][2], kv[j][2], sacc[i][j]);
                    sacc[i][j] = fmaf(qv[i][3], kv[j][3], sacc[i][j]);
                }
        }

        const f4 mv = *(const f4*)&mg[k0 + (tx << 2)];
        #pragma unroll
        for (int i = 0; i < 4; ++i) {
            const float lg0 = fmaf(mv[0], -1e9f, sacc[i][0] * 0.125f);
            const float lg1 = fmaf(mv[1], -1e9f, sacc[i][1] * 0.125f);
            const float lg2 = fmaf(mv[2], -1e9f, sacc[i][2] * 0.125f);
            const float lg3 = fmaf(mv[3], -1e9f, sacc[i][3] * 0.125f);
            float tm = fmaxf(fmaxf(lg0, lg1), fmaxf(lg2, lg3));
            #pragma unroll
            for (int o = 8; o >= 1; o >>= 1) tm = fmaxf(tm, __shfl_xor(tm, o, 64));
            const float nm = fmaxf(m_run[i], tm);
            float ts = __expf(lg0 - nm) + __expf(lg1 - nm) + __expf(lg2 - nm) + __expf(lg3 - nm);
            #pragma unroll
            for (int o = 8; o >= 1; o >>= 1) ts += __shfl_xor(ts, o, 64);
            l_run[i] = l_run[i] * __expf(m_run[i] - nm) + ts;
            m_run[i] = nm;
        }
    }

    float inv_l[4];
    #pragma unroll
    for (int i = 0; i < 4; ++i) inv_l[i] = 1.0f / l_run[i];

    // -------- phase 2: attn write + ctx accumulate --------
    float cacc[4][4] = {};
    float* __restrict__ attn_blk = attn + ((size_t)bh * Sn + q0) * Sn;

    for (int kt = 0; kt < Sn / 64; ++kt) {
        const int k0 = kt << 6;
        __syncthreads();
        #pragma unroll
        for (int p = 0; p < 4; ++p) {
            const int r = lr + (p << 4);
            *(f4*)&Ks[swz(r, lc)] = *(const f4*)&Kg[(size_t)(k0 + r) * DHn + lc];
            *(f4*)&Vs[swz(r, lc)] = *(const f4*)&Vg[(size_t)(k0 + r) * DHn + lc];
        }
        __syncthreads();

        float sacc[4][4] = {};
        #pragma unroll
        for (int d = 0; d < 64; d += 4) {
            f4 qv[4], kv[4];
            #pragma unroll
            for (int i = 0; i < 4; ++i) qv[i] = *(const f4*)&Qs[swz((ty << 2) + i, d)];
            #pragma unroll
            for (int j = 0; j < 4; ++j) kv[j] = *(const f4*)&Ks[swz((tx << 2) + j, d)];
            #pragma unroll
            for (int i = 0; i < 4; ++i)
                #pragma unroll
                for (int j = 0; j < 4; ++j) {
                    sacc[i][j] = fmaf(qv[i][0], kv[j][0], sacc[i][j]);
                    sacc[i][j] = fmaf(qv[i][1], kv[j][1], sacc[i][j]);
                    sacc[i][j] = fmaf(qv[i][2], kv[j][2], sacc[i][j]);
                    sacc[i][j] = fmaf(qv[i][3], kv[j][3], sacc[i][j]);
                }
        }

        const f4 mv = *(const f4*)&mg[k0 + (tx << 2)];
        #pragma unroll
        for (int i = 0; i < 4; ++i) {
            f4 pv;
            pv[0] = __expf(fmaf(mv[0], -1e9f, sacc[i][0] * 0.125f) - m_run[i]) * inv_l[i];
            pv[1] = __expf(fmaf(mv[1], -1e9f, sacc[i][1] * 0.125f) - m_run[i]) * inv_l[i];
            pv[2] = __expf(fmaf(mv[2], -1e9f, sacc[i][2] * 0.125f) - m_run[i]) * inv_l[i];
            pv[3] = __expf(fmaf(mv[3], -1e9f, sacc[i][3] * 0.125f) - m_run[i]) * inv_l[i];
            *(f4*)&attn_blk[(size_t)((ty << 2) + i) * Sn + k0 + (tx << 2)] = pv;
            *(f4*)&Ps[swz((ty << 2) + i, tx << 2)] = pv;
        }
        __syncthreads();

        #pragma unroll
        for (int kc = 0; kc < 64; kc += 4) {
            f4 pr[4], vr[4];
            #pragma unroll
            for (int i = 0; i < 4; ++i) pr[i] = *(const f4*)&Ps[swz((ty << 2) + i, kc)];
            #pragma unroll
            for (int qq = 0; qq < 4; ++qq) vr[qq] = *(const f4*)&Vs[swz(kc + qq, tx << 2)];
            #pragma unroll
            for (int i = 0; i < 4; ++i)
                #pragma unroll
                for (int j = 0; j < 4; ++j) {
                    cacc[i][j] = fmaf(pr[i][0], vr[0][j], cacc[i][j]);
                    cacc[i][j] = fmaf(pr[i][1], vr[1][j], cacc[i][j]);
                    cacc[i][j] = fmaf(pr[i][2], vr[2][j], cacc[i][j]);
                    cacc[i][j] = fmaf(pr[i][3], vr[3][j], cacc[i][j]);
                }
        }
    }

    #pragma unroll
    for (int i = 0; i < 4; ++i) {
        const int s = q0 + (ty << 2) + i;
        f4 o;
        o[0] = cacc[i][0]; o[1] = cacc[i][1]; o[2] = cacc[i][2]; o[3] = cacc[i][3];
        *(f4*)&ctx[((size_t)b * Sn + s) * Dn + (h << 6) + (tx << 2)] = o;
    }
}

extern "C" void kernel_launch(void* const* d_in, const int* in_sizes, int n_in,
                              void* d_out, int out_size, void* d_ws, size_t ws_size,
                              hipStream_t stream)
{
    const float* v_in = (const float*)d_in[0];
    const float* k_in = (const float*)d_in[1];
    const float* q_in = (const float*)d_in[2];
    const float* mask = (const float*)d_in[3];
    const float* Wq   = (const float*)d_in[4];
    const float* bq   = (const float*)d_in[5];
    const float* Wk   = (const float*)d_in[6];
    const float* bk   = (const float*)d_in[7];
    const float* Wv   = (const float*)d_in[8];
    const float* bv   = (const float*)d_in[9];
    const float* Wo   = (const float*)d_in[10];
    const float* bo   = (const float*)d_in[11];

    float* out  = (float*)d_out;                       // [B,S,D_MODEL]
    float* attn = out + (size_t)Bn * Sn * Dn;          // [B,H,S,S]

    const size_t headsz = (size_t)Bn * Hn * Sn * DHn;  // 4,194,304 floats
    float* qh  = (float*)d_ws;
    float* kh  = qh + headsz;
    float* vh  = kh + headsz;
    float* ctx = vh + headsz;                          // total 64 MiB

    qkv_proj_kernel<<<dim3(Dn / 64, (Bn * Sn) / 64, 3), 256, 0, stream>>>(
        q_in, k_in, v_in, Wq, bq, Wk, bk, Wv, bv, qh, kh, vh);
    attn_kernel<<<dim3(Sn / 64, Bn * Hn), 256, 0, stream>>>(qh, kh, vh, mask, attn, ctx);
    oproj_kernel<<<dim3(Dn / 64, (Bn * Sn) / 64), 256, 0, stream>>>(ctx, Wo, bo, out);
}

// Round 2
// 420.314 us; speedup vs baseline: 4.3156x; 4.3156x over previous
//
#include <hip/hip_runtime.h>
#include <cstdint>
#include <cstddef>

typedef __attribute__((ext_vector_type(4))) float f4;
typedef __attribute__((ext_vector_type(8))) short bf16x8;
typedef __attribute__((ext_vector_type(8))) unsigned short u16x8;

// ---------------- helpers ----------------
__device__ __forceinline__ unsigned short f2bf(float x) {
    unsigned u = __float_as_uint(x);
    u += 0x7fffu + ((u >> 16) & 1u);
    return (unsigned short)(u >> 16);
}
__device__ __forceinline__ float bf2f(unsigned short h) {
    return __uint_as_float(((unsigned)h) << 16);
}
__device__ __forceinline__ void gll16(const void* g, void* l) {
    __builtin_amdgcn_global_load_lds(
        (const __attribute__((address_space(1))) unsigned int*)g,
        (__attribute__((address_space(3))) unsigned int*)l, 16, 0, 0);
}
__device__ __forceinline__ f4 mfma16(bf16x8 a, bf16x8 b, f4 c) {
    return __builtin_amdgcn_mfma_f32_16x16x32_bf16(a, b, c, 0, 0, 0);
}

// ---------------- weight prep: W[K][N] fp32 -> W^T[N][K] bf16 hi/lo ----------------
__global__ __launch_bounds__(256)
void prep_w_kernel(const float* __restrict__ Wq, const float* __restrict__ Wk,
                   const float* __restrict__ Wv, const float* __restrict__ Wo,
                   unsigned short* __restrict__ wt_qkv, unsigned short* __restrict__ wt_o)
{
    const int w = blockIdx.z;
    const float* W = w == 0 ? Wq : (w == 1 ? Wk : (w == 2 ? Wv : Wo));
    unsigned short* hi = (w < 3) ? wt_qkv + (size_t)w * 2097152 : wt_o;
    unsigned short* lo = hi + 1048576;

    const int kb = blockIdx.x << 6, nb = blockIdx.y << 6;
    __shared__ float T[64][68];
    const int tid = threadIdx.x;
    {
        const int r = tid >> 2, c0 = (tid & 3) << 4;
        const float* src = W + (size_t)(kb + r) * 1024 + nb + c0;
        *(f4*)&T[r][c0 + 0]  = *(const f4*)(src + 0);
        *(f4*)&T[r][c0 + 4]  = *(const f4*)(src + 4);
        *(f4*)&T[r][c0 + 8]  = *(const f4*)(src + 8);
        *(f4*)&T[r][c0 + 12] = *(const f4*)(src + 12);
    }
    __syncthreads();
    {
        const int n = tid & 63, ks = (tid >> 6) << 4;
        unsigned short vh[16], vl[16];
        #pragma unroll
        for (int j = 0; j < 16; ++j) {
            const float x = T[ks + j][n];
            const unsigned short h = f2bf(x);
            vh[j] = h;
            vl[j] = f2bf(x - bf2f(h));
        }
        const size_t dst = (size_t)(nb + n) * 1024 + kb + ks;
        *(u16x8*)(hi + dst)     = *(u16x8*)&vh[0];
        *(u16x8*)(hi + dst + 8) = *(u16x8*)&vh[8];
        *(u16x8*)(lo + dst)     = *(u16x8*)&vl[0];
        *(u16x8*)(lo + dst + 8) = *(u16x8*)&vl[8];
    }
}

// ---------------- unified GEMM: C[4096][1024] = A(fp32) @ W (+bias) ----------------
// mode 0: head-split bf16 hi/lo out; mode 1: head-split bf16 hi only; mode 2: fp32 out
__device__ __forceinline__ void gemm_body(
    const float* __restrict__ A, const unsigned short* __restrict__ WtH,
    const unsigned short* __restrict__ WtL, const float* __restrict__ bias,
    unsigned short* __restrict__ o_hi, unsigned short* __restrict__ o_lo,
    float* __restrict__ o_f32, int mode, int bx, int by, unsigned char* lds)
{
    unsigned char* As = lds;            // [128 rows][128B]  (32 hi | 32 lo bf16, swizzled)
    unsigned char* Bs = lds + 16384;    // [128 rows][128B]
    const int tid = threadIdx.x;
    const int lane = tid & 63, wave = tid >> 6;
    const int wm = wave >> 1, wn = wave & 1;
    const int cx = lane & 15, lg = lane >> 4;
    const int m0 = by << 7, n0 = bx << 7;

    f4 acc[4][4];
    #pragma unroll
    for (int i = 0; i < 4; ++i)
        #pragma unroll
        for (int j = 0; j < 4; ++j) acc[i][j] = (f4){0.f, 0.f, 0.f, 0.f};

    const int arow = tid >> 1, ak0 = (tid & 1) << 4;
    const float* aptr = A + (size_t)(m0 + arow) * 1024 + ak0;
    const int sl0 = ak0 >> 3;          // 0 or 2
    const int sw = arow & 7;
    unsigned char* arow_base = As + arow * 128;

    for (int k0 = 0; k0 < 1024; k0 += 32) {
        const f4 a0 = *(const f4*)(aptr + k0);
        const f4 a1 = *(const f4*)(aptr + k0 + 4);
        const f4 a2 = *(const f4*)(aptr + k0 + 8);
        const f4 a3 = *(const f4*)(aptr + k0 + 12);
        __syncthreads();
        float xv[16];
        *(f4*)&xv[0] = a0; *(f4*)&xv[4] = a1; *(f4*)&xv[8] = a2; *(f4*)&xv[12] = a3;
        unsigned short hv[16], lv[16];
        #pragma unroll
        for (int j = 0; j < 16; ++j) {
            const unsigned short t = f2bf(xv[j]);
            hv[j] = t;
            lv[j] = f2bf(xv[j] - bf2f(t));
        }
        *(u16x8*)(arow_base + (((sl0 + 0) ^ sw) << 4)) = *(u16x8*)&hv[0];
        *(u16x8*)(arow_base + (((sl0 + 1) ^ sw) << 4)) = *(u16x8*)&hv[8];
        *(u16x8*)(arow_base + (((sl0 + 4) ^ sw) << 4)) = *(u16x8*)&lv[0];
        *(u16x8*)(arow_base + (((sl0 + 5) ^ sw) << 4)) = *(u16x8*)&lv[8];
        #pragma unroll
        for (int c = 0; c < 4; ++c) {
            const int L = (c << 12) + (tid << 4);
            const int row = L >> 7;
            const int phys = (L >> 4) & 7;
            const int logical = phys ^ (row & 7);
            const unsigned short* src = (logical < 4 ? WtH : WtL)
                + (size_t)(n0 + row) * 1024 + k0 + ((logical & 3) << 3);
            gll16(src, Bs + (c << 12) + (wave << 10));
        }
        __syncthreads();
        bf16x8 ah[4], al[4], bh[4], bl[4];
        #pragma unroll
        for (int t = 0; t < 4; ++t) {
            const int r = (wm << 6) + (t << 4) + cx;
            ah[t] = *(const bf16x8*)(As + r * 128 + (((lg + 0) ^ (r & 7)) << 4));
            al[t] = *(const bf16x8*)(As + r * 128 + (((lg + 4) ^ (r & 7)) << 4));
            const int n = (wn << 6) + (t << 4) + cx;
            bh[t] = *(const bf16x8*)(Bs + n * 128 + (((lg + 0) ^ (n & 7)) << 4));
            bl[t] = *(const bf16x8*)(Bs + n * 128 + (((lg + 4) ^ (n & 7)) << 4));
        }
        #pragma unroll
        for (int i = 0; i < 4; ++i)
            #pragma unroll
            for (int j = 0; j < 4; ++j) {
                acc[i][j] = mfma16(ah[i], bh[j], acc[i][j]);
                acc[i][j] = mfma16(ah[i], bl[j], acc[i][j]);
                acc[i][j] = mfma16(al[i], bh[j], acc[i][j]);
            }
    }

    float bv[4];
    #pragma unroll
    for (int j = 0; j < 4; ++j) bv[j] = bias[n0 + (wn << 6) + (j << 4) + cx];

    #pragma unroll
    for (int i = 0; i < 4; ++i)
        #pragma unroll
        for (int j = 0; j < 4; ++j) {
            const int n = n0 + (wn << 6) + (j << 4) + cx;
            #pragma unroll
            for (int r = 0; r < 4; ++r) {
                const float val = acc[i][j][r] + bv[j];
                const int m = m0 + (wm << 6) + (i << 4) + (lg << 2) + r;
                if (mode == 2) {
                    o_f32[(size_t)m * 1024 + n] = val;
                } else {
                    const int b = m >> 11, s = m & 2047, hh = n >> 6, d = n & 63;
                    const size_t idx = (((size_t)(b * 16 + hh)) * 2048 + s) * 64 + d;
                    const unsigned short t = f2bf(val);
                    o_hi[idx] = t;
                    if (mode == 0) o_lo[idx] = f2bf(val - bf2f(t));
                }
            }
        }
}

__global__ __launch_bounds__(256, 2)
void qkv_gemm_kernel(const float* __restrict__ q_in, const float* __restrict__ k_in,
                     const float* __restrict__ v_in,
                     const unsigned short* __restrict__ wt_qkv,
                     const float* __restrict__ bq, const float* __restrict__ bk,
                     const float* __restrict__ bv,
                     unsigned short* __restrict__ q_hi, unsigned short* __restrict__ q_lo,
                     unsigned short* __restrict__ k_hi, unsigned short* __restrict__ k_lo,
                     unsigned short* __restrict__ v_hi)
{
    __shared__ __align__(16) unsigned char lds[32768];
    const int z = blockIdx.z;
    const float* A = z == 0 ? q_in : (z == 1 ? k_in : v_in);
    const unsigned short* WtH = wt_qkv + (size_t)z * 2097152;
    const unsigned short* WtL = WtH + 1048576;
    const float* bias = z == 0 ? bq : (z == 1 ? bk : bv);
    unsigned short* ohi = z == 0 ? q_hi : (z == 1 ? k_hi : v_hi);
    unsigned short* olo = z == 0 ? q_lo : k_lo;
    gemm_body(A, WtH, WtL, bias, ohi, olo, nullptr, (z == 2) ? 1 : 0,
              blockIdx.x, blockIdx.y, lds);
}

__global__ __launch_bounds__(256, 2)
void out_gemm_kernel(const float* __restrict__ ctx, const unsigned short* __restrict__ wt_o,
                     const float* __restrict__ bo, float* __restrict__ out)
{
    __shared__ __align__(16) unsigned char lds[32768];
    gemm_body(ctx, wt_o, wt_o + 1048576, bo, nullptr, nullptr, out, 2,
              blockIdx.x, blockIdx.y, lds);
}

// ---------------- fused attention, MFMA (two-pass flash) ----------------
__global__ __launch_bounds__(256, 2)
void attn_mfma_kernel(const unsigned short* __restrict__ q_hi, const unsigned short* __restrict__ q_lo,
                      const unsigned short* __restrict__ k_hi, const unsigned short* __restrict__ k_lo,
                      const unsigned short* __restrict__ v_hi, const float* __restrict__ mask,
                      float* __restrict__ attn, float* __restrict__ ctx)
{
    __shared__ __align__(16) unsigned char lds[32768];
    unsigned char* Ks = lds;            // [64 rows][256B] (64 hi | 64 lo bf16, swizzled)
    unsigned char* Vs = lds + 16384;    // V^T [64 d][128B] (64 s bf16, swizzled)
    unsigned char* Ps = lds + 24576;    // P   [64 q][128B] (64 s bf16, swizzled)

    const int bh = blockIdx.x;
    const int b = bh >> 4, h = bh & 15;
    const int q0 = blockIdx.y << 6;
    const int tid = threadIdx.x, lane = tid & 63, wave = tid >> 6;
    const int cx = lane & 15, lg = lane >> 4;

    const size_t base = (size_t)bh * 2048 * 64;
    const float* mg = mask + (size_t)b * 2048;

    // ---- stage Q (into Ks buffer), pull frags to registers ----
    #pragma unroll
    for (int c = 0; c < 4; ++c) {
        const int L = (c << 12) + (tid << 4);
        const int row = L >> 8;
        const int phys = (L >> 4) & 15;
        const int logical = phys ^ (row & 7);
        const unsigned short* src = (logical < 8 ? q_hi : q_lo)
            + base + (size_t)(q0 + row) * 64 + ((logical & 7) << 3);
        gll16(src, Ks + (c << 12) + (wave << 10));
    }
    __syncthreads();
    bf16x8 qa_h[2], qa_l[2];
    {
        const int r = (wave << 4) + cx;
        const int sw = r & 7;
        #pragma unroll
        for (int ks = 0; ks < 2; ++ks) {
            const int sl = (ks << 2) + lg;
            qa_h[ks] = *(const bf16x8*)(Ks + r * 256 + ((sl ^ sw) << 4));
            qa_l[ks] = *(const bf16x8*)(Ks + r * 256 + (((sl + 8) ^ sw) << 4));
        }
    }
    __syncthreads();

    float m_run[4], l_run[4];
    #pragma unroll
    for (int r = 0; r < 4; ++r) { m_run[r] = -3.0e38f; l_run[r] = 0.f; }

    // -------- phase 1: row stats --------
    for (int kt = 0; kt < 32; ++kt) {
        const int k0 = kt << 6;
        #pragma unroll
        for (int c = 0; c < 4; ++c) {
            const int L = (c << 12) + (tid << 4);
            const int row = L >> 8;
            const int phys = (L >> 4) & 15;
            const int logical = phys ^ (row & 7);
            const unsigned short* src = (logical < 8 ? k_hi : k_lo)
                + base + (size_t)(k0 + row) * 64 + ((logical & 7) << 3);
            gll16(src, Ks + (c << 12) + (wave << 10));
        }
        __syncthreads();
        f4 sacc[4];
        #pragma unroll
        for (int nt = 0; nt < 4; ++nt) sacc[nt] = (f4){0.f, 0.f, 0.f, 0.f};
        #pragma unroll
        for (int nt = 0; nt < 4; ++nt) {
            const int kr = (nt << 4) + cx;
            const int sw2 = kr & 7;
            #pragma unroll
            for (int ks = 0; ks < 2; ++ks) {
                const int sl = (ks << 2) + lg;
                const bf16x8 kh8 = *(const bf16x8*)(Ks + kr * 256 + ((sl ^ sw2) << 4));
                const bf16x8 kl8 = *(const bf16x8*)(Ks + kr * 256 + (((sl + 8) ^ sw2) << 4));
                sacc[nt] = mfma16(qa_h[ks], kh8, sacc[nt]);
                sacc[nt] = mfma16(qa_h[ks], kl8, sacc[nt]);
                sacc[nt] = mfma16(qa_l[ks], kh8, sacc[nt]);
            }
        }
        float mk[4];
        #pragma unroll
        for (int nt = 0; nt < 4; ++nt) mk[nt] = mg[k0 + (nt << 4) + cx] * -1e9f;
        #pragma unroll
        for (int r = 0; r < 4; ++r) {
            const float l0 = fmaf(sacc[0][r], 0.125f, mk[0]);
            const float l1 = fmaf(sacc[1][r], 0.125f, mk[1]);
            const float l2 = fmaf(sacc[2][r], 0.125f, mk[2]);
            const float l3 = fmaf(sacc[3][r], 0.125f, mk[3]);
            float tm = fmaxf(fmaxf(l0, l1), fmaxf(l2, l3));
            tm = fmaxf(tm, __shfl_xor(tm, 1));
            tm = fmaxf(tm, __shfl_xor(tm, 2));
            tm = fmaxf(tm, __shfl_xor(tm, 4));
            tm = fmaxf(tm, __shfl_xor(tm, 8));
            const float nm = fmaxf(m_run[r], tm);
            float ts = __expf(l0 - nm) + __expf(l1 - nm) + __expf(l2 - nm) + __expf(l3 - nm);
            ts += __shfl_xor(ts, 1);
            ts += __shfl_xor(ts, 2);
            ts += __shfl_xor(ts, 4);
            ts += __shfl_xor(ts, 8);
            l_run[r] = l_run[r] * __expf(m_run[r] - nm) + ts;
            m_run[r] = nm;
        }
        __syncthreads();
    }

    float inv_l[4];
    #pragma unroll
    for (int r = 0; r < 4; ++r) inv_l[r] = 1.0f / l_run[r];

    f4 cacc[4];
    #pragma unroll
    for (int nt = 0; nt < 4; ++nt) cacc[nt] = (f4){0.f, 0.f, 0.f, 0.f};

    // -------- phase 2: attn write + PV --------
    for (int kt = 0; kt < 32; ++kt) {
        const int k0 = kt << 6;
        #pragma unroll
        for (int c = 0; c < 4; ++c) {
            const int L = (c << 12) + (tid << 4);
            const int row = L >> 8;
            const int phys = (L >> 4) & 15;
            const int logical = phys ^ (row & 7);
            const unsigned short* src = (logical < 8 ? k_hi : k_lo)
                + base + (size_t)(k0 + row) * 64 + ((logical & 7) << 3);
            gll16(src, Ks + (c << 12) + (wave << 10));
        }
        {   // V stage: transpose into Vs
            const int s = tid & 63, d0 = (tid >> 6) << 4;
            const unsigned short* vsrc = v_hi + base + (size_t)(k0 + s) * 64 + d0;
            const u16x8 v0 = *(const u16x8*)vsrc;
            const u16x8 v1 = *(const u16x8*)(vsrc + 8);
            const int sl = s >> 3, sb = (s & 7) << 1;
            #pragma unroll
            for (int j = 0; j < 8; ++j) {
                const int d = d0 + j;
                *(unsigned short*)(Vs + d * 128 + ((sl ^ (d & 7)) << 4) + sb) = v0[j];
                const int d2 = d0 + 8 + j;
                *(unsigned short*)(Vs + d2 * 128 + ((sl ^ (d2 & 7)) << 4) + sb) = v1[j];
            }
        }
        __syncthreads();
        f4 sacc[4];
        #pragma unroll
        for (int nt = 0; nt < 4; ++nt) sacc[nt] = (f4){0.f, 0.f, 0.f, 0.f};
        #pragma unroll
        for (int nt = 0; nt < 4; ++nt) {
            const int kr = (nt << 4) + cx;
            const int sw2 = kr & 7;
            #pragma unroll
            for (int ks = 0; ks < 2; ++ks) {
                const int sl = (ks << 2) + lg;
                const bf16x8 kh8 = *(const bf16x8*)(Ks + kr * 256 + ((sl ^ sw2) << 4));
                const bf16x8 kl8 = *(const bf16x8*)(Ks + kr * 256 + (((sl + 8) ^ sw2) << 4));
                sacc[nt] = mfma16(qa_h[ks], kh8, sacc[nt]);
                sacc[nt] = mfma16(qa_h[ks], kl8, sacc[nt]);
                sacc[nt] = mfma16(qa_l[ks], kh8, sacc[nt]);
            }
        }
        float mk[4];
        #pragma unroll
        for (int nt = 0; nt < 4; ++nt) mk[nt] = mg[k0 + (nt << 4) + cx] * -1e9f;
        #pragma unroll
        for (int nt = 0; nt < 4; ++nt) {
            #pragma unroll
            for (int r = 0; r < 4; ++r) {
                const float lgt = fmaf(sacc[nt][r], 0.125f, mk[nt]);
                const float p = __expf(lgt - m_run[r]) * inv_l[r];
                const int qrow = (wave << 4) + (lg << 2) + r;
                attn[((size_t)bh * 2048 + q0 + qrow) * 2048 + k0 + (nt << 4) + cx] = p;
                const int col = (nt << 4) + cx;
                *(unsigned short*)(Ps + qrow * 128 + (((col >> 3) ^ (qrow & 7)) << 4)
                                   + ((col & 7) << 1)) = f2bf(p);
            }
        }
        __syncthreads();
        #pragma unroll
        for (int ks = 0; ks < 2; ++ks) {
            const int qr = (wave << 4) + cx;
            const int sl = (ks << 2) + lg;
            const bf16x8 pa = *(const bf16x8*)(Ps + qr * 128 + ((sl ^ (qr & 7)) << 4));
            #pragma unroll
            for (int nt = 0; nt < 4; ++nt) {
                const int dr = (nt << 4) + cx;
                const bf16x8 vb = *(const bf16x8*)(Vs + dr * 128 + ((sl ^ (dr & 7)) << 4));
                cacc[nt] = mfma16(pa, vb, cacc[nt]);
            }
        }
        __syncthreads();
    }

    #pragma unroll
    for (int nt = 0; nt < 4; ++nt)
        #pragma unroll
        for (int r = 0; r < 4; ++r) {
            const int s = q0 + (wave << 4) + (lg << 2) + r;
            const int d = (h << 6) + (nt << 4) + cx;
            ctx[((size_t)b * 2048 + s) * 1024 + d] = cacc[nt][r];
        }
}

// ---------------- launcher ----------------
extern "C" void kernel_launch(void* const* d_in, const int* in_sizes, int n_in,
                              void* d_out, int out_size, void* d_ws, size_t ws_size,
                              hipStream_t stream)
{
    const float* v_in = (const float*)d_in[0];
    const float* k_in = (const float*)d_in[1];
    const float* q_in = (const float*)d_in[2];
    const float* mask = (const float*)d_in[3];
    const float* Wq = (const float*)d_in[4];
    const float* bq = (const float*)d_in[5];
    const float* Wk = (const float*)d_in[6];
    const float* bk = (const float*)d_in[7];
    const float* Wv = (const float*)d_in[8];
    const float* bv = (const float*)d_in[9];
    const float* Wo = (const float*)d_in[10];
    const float* bo = (const float*)d_in[11];

    float* out  = (float*)d_out;                    // [2,2048,1024]
    float* attn = out + (size_t)4194304;            // [2,16,2048,2048]

    unsigned char* ws = (unsigned char*)d_ws;
    unsigned short* wt_o = (unsigned short*)(ws);                   // 4 MB (hi|lo)
    unsigned short* q_hi = (unsigned short*)(ws + (size_t)(4)  * 1048576);
    unsigned short* q_lo = (unsigned short*)(ws + (size_t)(12) * 1048576);
    unsigned short* k_hi = (unsigned short*)(ws + (size_t)(20) * 1048576);
    unsigned short* k_lo = (unsigned short*)(ws + (size_t)(28) * 1048576);
    unsigned short* v_hi = (unsigned short*)(ws + (size_t)(36) * 1048576);
    float* ctx = (float*)(ws + (size_t)(44) * 1048576);             // 16 MB -> ends at 60 MB

    // Wq/Wk/Wv transposed weights live in the tail of the attn output region
    // (dead scratch until attn_mfma_kernel overwrites it afterwards).
    unsigned short* wt_qkv = (unsigned short*)(attn + (size_t)100 * 1048576);

    prep_w_kernel<<<dim3(16, 16, 4), 256, 0, stream>>>(Wq, Wk, Wv, Wo, wt_qkv, wt_o);
    qkv_gemm_kernel<<<dim3(8, 32, 3), 256, 0, stream>>>(q_in, k_in, v_in, wt_qkv,
                                                        bq, bk, bv,
                                                        q_hi, q_lo, k_hi, k_lo, v_hi);
    attn_mfma_kernel<<<dim3(32, 32), 256, 0, stream>>>(q_hi, q_lo, k_hi, k_lo, v_hi,
                                                       mask, attn, ctx);
    out_gemm_kernel<<<dim3(8, 32), 256, 0, stream>>>(ctx, wt_o, bo, out);
}